// Round 2
// baseline (1077.604 us; speedup 1.0000x reference)
//
#include <hip/hip_runtime.h>
#include <math.h>

#define D_VOCAB 50257
#define D_MODEL 768
#define SCAN_K 8   // independent loads in flight per wave per outer iteration

// Phase 1: flat uint4 scan of the one-hot tokens array.
// Key point: SCAN_K independent coalesced loads are issued before ANY use,
// so each wave keeps 8 loads in flight (the previous version's load->branch
// dependency capped it at 1 outstanding load -> latency-bound ~0.8 TB/s).
// One-hot entries are exactly 0.0f or 1.0f, so an integer-OR test is exact
// (no -0.0f can occur).
__global__ void find_indices(const uint4* __restrict__ tok4, unsigned n4,
                             int* __restrict__ idx) {
    unsigned tid = blockIdx.x * blockDim.x + threadIdx.x;
    unsigned stride = gridDim.x * blockDim.x;
    unsigned step = SCAN_K * stride;
    unsigned i = tid;

    for (; i + (SCAN_K - 1) * stride < n4; i += step) {
        uint4 v[SCAN_K];
        #pragma unroll
        for (int k = 0; k < SCAN_K; ++k)
            v[k] = tok4[i + (unsigned)k * stride];

        unsigned any = 0;
        #pragma unroll
        for (int k = 0; k < SCAN_K; ++k)
            any |= (v[k].x | v[k].y | v[k].z | v[k].w);

        if (any) {                      // taken ~once per ~3000 iterations
            #pragma unroll
            for (int k = 0; k < SCAN_K; ++k) {
                if (v[k].x | v[k].y | v[k].z | v[k].w) {
                    unsigned flat = (i + (unsigned)k * stride) * 4u;
                    if (v[k].x) { unsigned f = flat + 0u; unsigned r = f / D_VOCAB; idx[r] = (int)(f - r * D_VOCAB); }
                    if (v[k].y) { unsigned f = flat + 1u; unsigned r = f / D_VOCAB; idx[r] = (int)(f - r * D_VOCAB); }
                    if (v[k].z) { unsigned f = flat + 2u; unsigned r = f / D_VOCAB; idx[r] = (int)(f - r * D_VOCAB); }
                    if (v[k].w) { unsigned f = flat + 3u; unsigned r = f / D_VOCAB; idx[r] = (int)(f - r * D_VOCAB); }
                }
            }
        }
    }
    // tail (<2% of the data): single-load scan
    for (; i < n4; i += stride) {
        uint4 v = tok4[i];
        if (v.x | v.y | v.z | v.w) {
            unsigned flat = i * 4u;
            if (v.x) { unsigned f = flat + 0u; unsigned r = f / D_VOCAB; idx[r] = (int)(f - r * D_VOCAB); }
            if (v.y) { unsigned f = flat + 1u; unsigned r = f / D_VOCAB; idx[r] = (int)(f - r * D_VOCAB); }
            if (v.z) { unsigned f = flat + 2u; unsigned r = f / D_VOCAB; idx[r] = (int)(f - r * D_VOCAB); }
            if (v.w) { unsigned f = flat + 3u; unsigned r = f / D_VOCAB; idx[r] = (int)(f - r * D_VOCAB); }
        }
    }
}

// Phase 2: out[row, :] = W[idx[row], :] * sqrt(D_MODEL) + bias.
__global__ void gather_embed(const int* __restrict__ idx,
                             const float4* __restrict__ W4,
                             const float4* __restrict__ b4,
                             float4* __restrict__ out4,
                             unsigned n4out) {
    unsigned i = blockIdx.x * blockDim.x + threadIdx.x;
    if (i >= n4out) return;
    const float scale = sqrtf((float)D_MODEL);  // constant-folded
    const unsigned DM4 = D_MODEL / 4;
    unsigned row = i / DM4;
    unsigned d4 = i - row * DM4;
    unsigned v = (unsigned)idx[row];
    float4 w = W4[v * DM4 + d4];
    float4 b = b4[d4];
    float4 o;
    o.x = w.x * scale + b.x;
    o.y = w.y * scale + b.y;
    o.z = w.z * scale + b.z;
    o.w = w.w * scale + b.w;
    out4[i] = o;
}

extern "C" void kernel_launch(void* const* d_in, const int* in_sizes, int n_in,
                              void* d_out, int out_size, void* d_ws, size_t ws_size,
                              hipStream_t stream) {
    const float* tokens = (const float*)d_in[0];        // [B*P, V] fp32 one-hot
    const float* weights = (const float*)d_in[1];       // [V, D] fp32
    const float* bias = (const float*)d_in[2];          // [D] fp32
    float* out = (float*)d_out;                          // [B*P, D] fp32
    int* idx = (int*)d_ws;                               // [B*P] int32 scratch

    unsigned n_tok = (unsigned)in_sizes[0];
    unsigned n4 = n_tok / 4u;                            // 51,463,168 — exact

    // 8192 blocks x 256 thr = 2M threads; each outer iter covers 16M uint4s,
    // ~3 full iterations + small tail.
    find_indices<<<8192, 256, 0, stream>>>((const uint4*)tokens, n4, idx);

    unsigned n4out = (unsigned)out_size / 4u;            // 786,432
    unsigned blocks2 = (n4out + 255u) / 256u;
    gather_embed<<<blocks2, 256, 0, stream>>>(idx, (const float4*)weights,
                                              (const float4*)bias,
                                              (float4*)out, n4out);
}

// Round 3
// 1027.725 us; speedup vs baseline: 1.0485x; 1.0485x over previous
//
#include <hip/hip_runtime.h>
#include <math.h>

#define D_VOCAB 50257
#define D_MODEL 768
#define DM4 (D_MODEL / 4)          // 192 float4 per output row
#define BLK 256
#define CH 8                        // float4 loads per thread per chunk
#define CHUNK4 (BLK * CH)           // 2048 float4 = 32 KB per chunk
#define SENT 0xFFFFFFFFu

// One block per (batch,pos) row. Scan the row's one-hot stripe in 32 KB
// chunks with early exit (expected ~66% of the row read instead of 100%),
// then directly emit out[row,:] = W[col,:]*sqrt(768) + bias.
//
// Correctness notes:
//  - Row base rb*4B is only 4B-aligned (50257 is odd), so we scan from
//    rb&~3 (16B-aligned). Elements in the pad belong to the neighbor row;
//    finds outside [rb, re) are ignored (the neighbor's own block finds them).
//  - s_state is written only in the compute phase (between barrier pairs) and
//    read only between the two barriers -> race-free, and the break decision
//    is uniform across the block (no barrier divergence).
//  - One-hot values are exactly 0.0f/1.0f, so integer-nonzero tests are exact.
__global__ __launch_bounds__(BLK) void embed_fused(
    const uint4*  __restrict__ tok4,
    const float4* __restrict__ W4,
    const float4* __restrict__ b4,
    float4*       __restrict__ out4)
{
    __shared__ unsigned s_state;    // SENT = not found; else = column index

    const unsigned row = blockIdx.x;
    const unsigned t   = threadIdx.x;

    if (t == 0) s_state = SENT;
    __syncthreads();

    const unsigned rb  = row * (unsigned)D_VOCAB;   // row start, float units
    const unsigned re  = rb + (unsigned)D_VOCAB;    // row end (exclusive)
    const unsigned a04 = rb >> 2;                   // aligned start, float4 units
    const unsigned e4  = (re + 3u) >> 2;            // aligned end,   float4 units

    for (unsigned base4 = a04; base4 < e4; base4 += CHUNK4) {
        // ---- issue all 8 loads before any use (MLP) ----
        uint4 v[CH];
        unsigned p4[CH];
        #pragma unroll
        for (int k = 0; k < CH; ++k) {
            p4[k] = base4 + (unsigned)k * BLK + t;
            if (p4[k] < e4) v[k] = tok4[p4[k]];
            else            v[k] = make_uint4(0u, 0u, 0u, 0u);
        }
        // ---- check ----
        #pragma unroll
        for (int k = 0; k < CH; ++k) {
            if (v[k].x | v[k].y | v[k].z | v[k].w) {   // rare (~1/12566 lanes)
                unsigned f = p4[k] * 4u;
                unsigned hit = SENT;
                if (v[k].x && f + 0u >= rb && f + 0u < re) hit = f + 0u;
                if (v[k].y && f + 1u >= rb && f + 1u < re) hit = f + 1u;
                if (v[k].z && f + 2u >= rb && f + 2u < re) hit = f + 2u;
                if (v[k].w && f + 3u >= rb && f + 3u < re) hit = f + 3u;
                if (hit != SENT) s_state = hit - rb;   // exactly one writer/row
            }
        }
        __syncthreads();                 // (1) this chunk's write visible to all
        bool done = (s_state != SENT);   // read window: uniform value
        __syncthreads();                 // (2) no next-chunk write before all reads
        if (done) break;
    }

    // s_state now holds the column (guaranteed found: our element is in-range).
    const unsigned col = s_state;
    if (t < DM4) {
        const float scale = sqrtf((float)D_MODEL);   // constant-folded
        float4 w = W4[col * (unsigned)DM4 + t];
        float4 b = b4[t];
        float4 o;
        o.x = fmaf(w.x, scale, b.x);
        o.y = fmaf(w.y, scale, b.y);
        o.z = fmaf(w.z, scale, b.z);
        o.w = fmaf(w.w, scale, b.w);
        out4[row * (unsigned)DM4 + t] = o;
    }
}

extern "C" void kernel_launch(void* const* d_in, const int* in_sizes, int n_in,
                              void* d_out, int out_size, void* d_ws, size_t ws_size,
                              hipStream_t stream) {
    const float* tokens  = (const float*)d_in[0];   // [B*P, V] fp32 one-hot
    const float* weights = (const float*)d_in[1];   // [V, D] fp32
    const float* bias    = (const float*)d_in[2];   // [D] fp32
    float* out = (float*)d_out;                     // [B*P, D] fp32

    const unsigned n_rows = (unsigned)(out_size / D_MODEL);   // 4096
    embed_fused<<<n_rows, BLK, 0, stream>>>((const uint4*)tokens,
                                            (const float4*)weights,
                                            (const float4*)bias,
                                            (float4*)out);
}

// Round 4
// 1021.121 us; speedup vs baseline: 1.0553x; 1.0065x over previous
//
#include <hip/hip_runtime.h>
#include <math.h>

#define D_VOCAB 50257
#define D_MODEL 768
#define DM4 (D_MODEL / 4)     // 192 float4 per output row
#define CH 16                  // uint4 loads in flight per lane per chunk (16 KB/wave-chunk)
#define SENT 0xFFFFFFFFu

// One WAVE per (batch,pos) row — no barriers, no LDS. Each wave scans its
// row's one-hot stripe in 16 KB chunks with early exit; waves are fully
// autonomous so a wave's vmcnt drain never stalls the other 15 waves/CU.
// Found-column broadcast is wave-level (__ballot + __shfl). The gather
// (out[row,:] = W[col,:]*sqrt(768) + bias) is fused into the same wave.
//
// Correctness:
//  - Row base rb (float units) is only 4B-aligned (50257 odd); scan starts at
//    the 16B-aligned float4 floor(rb/4). Nonzero pad elements belong to a
//    neighbor row and are filtered by the [rb, re) range check; if a chunk's
//    only nonzero was a pad element, ballot==0 and the scan continues.
//  - One-hot values are exactly 0.0f or 1.0f -> integer-nonzero test is exact.
//  - ballot is wave-uniform, so the `break` is wave-uniform (no divergence).
__global__ __launch_bounds__(256) void embed_wave(
    const uint4*  __restrict__ tok4,
    const float4* __restrict__ W4,
    const float4* __restrict__ b4,
    float4*       __restrict__ out4,
    unsigned n_rows)
{
    const unsigned wave = blockIdx.x * 4u + (threadIdx.x >> 6);
    const unsigned lane = threadIdx.x & 63u;
    if (wave >= n_rows) return;
    const unsigned row = wave;

    const unsigned rb = row * (unsigned)D_VOCAB;   // row start, float units
    const unsigned re = rb + (unsigned)D_VOCAB;    // row end (exclusive)
    const unsigned a4 = rb >> 2;                   // aligned start, float4 units
    const unsigned e4 = (re + 3u) >> 2;            // aligned end,   float4 units

    unsigned col = 0;
    for (unsigned base = a4; base < e4; base += 64u * CH) {
        // ---- issue all CH loads before any use (per-wave MLP) ----
        uint4 v[CH];
        #pragma unroll
        for (int k = 0; k < CH; ++k) {
            unsigned p = base + (unsigned)k * 64u + lane;
            v[k] = (p < e4) ? tok4[p] : make_uint4(0u, 0u, 0u, 0u);
        }
        unsigned any = 0;
        #pragma unroll
        for (int k = 0; k < CH; ++k)
            any |= (v[k].x | v[k].y | v[k].z | v[k].w);

        if (__any(any != 0u)) {                    // VCC test, no barrier
            unsigned hit = SENT;
            #pragma unroll
            for (int k = 0; k < CH; ++k) {
                if (v[k].x | v[k].y | v[k].z | v[k].w) {
                    unsigned f = (base + (unsigned)k * 64u + lane) * 4u;
                    if (v[k].x && f + 0u >= rb && f + 0u < re) hit = f + 0u - rb;
                    if (v[k].y && f + 1u >= rb && f + 1u < re) hit = f + 1u - rb;
                    if (v[k].z && f + 2u >= rb && f + 2u < re) hit = f + 2u - rb;
                    if (v[k].w && f + 3u >= rb && f + 3u < re) hit = f + 3u - rb;
                }
            }
            unsigned long long bal = __ballot(hit != SENT);
            if (bal) {                             // wave-uniform
                int src = __ffsll(bal) - 1;
                col = __shfl((int)hit, src, 64);
                break;
            }
            // else: nonzero was a neighbor-row pad element; keep scanning
        }
    }

    // ---- fused gather: 192 float4 across 64 lanes = 3 per lane ----
    const float scale = sqrtf((float)D_MODEL);     // constant-folded
    #pragma unroll
    for (int j = 0; j < 3; ++j) {
        unsigned d = lane + 64u * (unsigned)j;
        float4 w = W4[(unsigned)col * (unsigned)DM4 + d];
        float4 b = b4[d];
        float4 o;
        o.x = fmaf(w.x, scale, b.x);
        o.y = fmaf(w.y, scale, b.y);
        o.z = fmaf(w.z, scale, b.z);
        o.w = fmaf(w.w, scale, b.w);
        out4[row * (unsigned)DM4 + d] = o;
    }
}

extern "C" void kernel_launch(void* const* d_in, const int* in_sizes, int n_in,
                              void* d_out, int out_size, void* d_ws, size_t ws_size,
                              hipStream_t stream) {
    const float* tokens  = (const float*)d_in[0];   // [B*P, V] fp32 one-hot
    const float* weights = (const float*)d_in[1];   // [V, D] fp32
    const float* bias    = (const float*)d_in[2];   // [D] fp32
    float* out = (float*)d_out;                     // [B*P, D] fp32

    const unsigned n_rows = (unsigned)(out_size / D_MODEL);   // 4096
    const unsigned blocks = (n_rows + 3u) / 4u;               // 4 waves/block
    embed_wave<<<blocks, 256, 0, stream>>>((const uint4*)tokens,
                                           (const float4*)weights,
                                           (const float4*)bias,
                                           (float4*)out, n_rows);
}